// Round 9
// baseline (77.016 us; speedup 1.0000x reference)
//
#include <hip/hip_runtime.h>

// DensityLoss: B=8, N=4096, radius=0.1, NSAMPLE=9, TOPK=5, H=0.12, EPS=1e-12
// Output: scalar mean over [B,N,TOPK-1] of (RADIUS - sqrt(ds)*exp(-ds/H^2))
//
// R9: grid-binned ball query, 3rd attempt. Fixes vs R6/R7 (both passed
// correctness, both were slow for identified implementation reasons):
//  - packed float4(x,y,z,idx) cells -> 1 ds_read_b128 per candidate (R6 did
//    4 scattered b32 reads).
//  - flat-j candidate mapping (R6-style, ~86% lane util; R7's run-wise was
//    ~19%) with the 9-run (cum,adj) table forced into SGPRs via
//    readfirstlane -> cndmask chain is 2 VALU/run, no register arrays.
//  - rank-by-index via v_readlane loop (independent, register-only); R6's
//    serial dependent-LDS loop was ~60cyc/iter.
//  - NO __launch_bounds__ min-wave forcing (R7's spill suspect). LDS
//    ~76.7 KB -> 2 blocks/CU naturally.
// Semantics: qualifiers from the 27-cell neighborhood == ball-query set
// (cell edge = radius); rank by original index; slot=rank<9, fill=rank-0 ds.

#define NB 8
#define NPTS 4096
#define NS 9
#define RAD2 0.01f
#define H2 0.0144f
#define EPSV 1e-12f
#define SCALE (1.0f / 131072.0f)   // 1/(B*N*(TOPK-1)) = 1/(8*4096*4)
#define QCAP 64                    // qualifier cap (E=17, P(>64) ~ 0)

__global__ __launch_bounds__(1024) void density_loss_kernel(
    const float* __restrict__ pred, float* __restrict__ part) {
    __shared__ __align__(16) float4 sp[NPTS];   // binned (x,y,z,idx-bits) 64KB
    __shared__ int cellStart[1008];   // counts, then in-place exclusive prefix
    __shared__ float qds[16][QCAP];   // per-wave qualifier ds (4KB)
    __shared__ unsigned short qid[16][QCAP];    // per-wave qualifier idx (2KB)
    __shared__ float buf[64][NS];     // per-point slots (index-rank order)
    __shared__ int cnts[64];
    __shared__ int wtot[16], wtote[16];

    const int tid  = threadIdx.x;
    const int lane = tid & 63;
    const int wid  = tid >> 6;
    const int b    = blockIdx.x >> 6;                        // 64 blocks/batch
    const int nbase = ((blockIdx.x & 63) << 6) + (wid << 2); // 4 queries/wave
    const float* src = pred + (size_t)b * (NPTS * 3);

    if (tid < 1008) cellStart[tid] = 0;
    __syncthreads();

    // ---- Load 4 points/thread (coalesced float4), cell-id, count.
    float px[4], py[4], pz[4];
    int cid[4], off[4];
    {
        const float4* s4 = (const float4*)src;
        float4 A = s4[3 * tid], Bq = s4[3 * tid + 1], Cq = s4[3 * tid + 2];
        px[0] = A.x;  py[0] = A.y;  pz[0] = A.z;
        px[1] = A.w;  py[1] = Bq.x; pz[1] = Bq.y;
        px[2] = Bq.z; py[2] = Bq.w; pz[2] = Cq.x;
        px[3] = Cq.y; py[3] = Cq.z; pz[3] = Cq.w;
        #pragma unroll
        for (int k = 0; k < 4; ++k) {
            int cx = min((int)(px[k] * 10.0f), 9);
            int cy = min((int)(py[k] * 10.0f), 9);
            int cz = min((int)(pz[k] * 10.0f), 9);
            cid[k] = (cx * 10 + cy) * 10 + cz;
            off[k] = atomicAdd(&cellStart[cid[k]], 1);
        }
    }
    __syncthreads();

    // ---- In-place exclusive scan of cellStart (proven in R7).
    {
        int val = (tid < 1000) ? cellStart[tid] : 0;
        int incl = val;
        #pragma unroll
        for (int o = 1; o < 64; o <<= 1) {
            int t = __shfl_up(incl, o, 64);
            if (lane >= o) incl += t;
        }
        if (lane == 63) wtot[wid] = incl;
        __syncthreads();   // all reads done before in-place writes
        if (wid == 0) {
            int wv = (lane < 16) ? wtot[lane] : 0;
            int wi = wv;
            #pragma unroll
            for (int o = 1; o < 16; o <<= 1) {
                int t = __shfl_up(wi, o, 64);
                if (lane >= o) wi += t;
            }
            if (lane < 16) wtote[lane] = wi - wv;
        }
        __syncthreads();
        if (tid < 1008) cellStart[tid] = wtote[wid] + incl - val;
    }
    __syncthreads();

    // ---- Scatter into binned packed array.
    #pragma unroll
    for (int k = 0; k < 4; ++k) {
        int pos = cellStart[cid[k]] + off[k];
        sp[pos] = (float4){px[k], py[k], pz[k], __int_as_float((tid << 2) + k)};
    }
    __syncthreads();

    // ---- Query phase: 4 queries/wave, flat-j over the 9 z-runs.
    for (int q = 0; q < 4; ++q) {
        const int n = nbase + q;
        const float qx = src[3 * n], qy = src[3 * n + 1], qz = src[3 * n + 2];
        const int cx = min((int)(qx * 10.0f), 9);
        const int cy = min((int)(qy * 10.0f), 9);
        const int cz = min((int)(qz * 10.0f), 9);
        const int z0 = max(cz - 1, 0);
        const int zext = min(cz + 1, 9) - z0 + 1;

        // 9-run table in SGPRs: cum[u] = exclusive total, adj[u] = start-cum.
        int cum1, cum2, cum3, cum4, cum5, cum6, cum7, cum8;
        int adj0, adj1, adj2, adj3, adj4, adj5, adj6, adj7, adj8;
        int total = 0;
        #pragma unroll
        for (int u = 0; u < 9; ++u) {
            const int ix = cx + (u / 3) - 1;
            const int iy = cy + (u % 3) - 1;
            const bool ok = (unsigned)ix <= 9u && (unsigned)iy <= 9u;
            const int c0 = ok ? ((ix * 10 + iy) * 10 + z0) : 0;
            const int s = __builtin_amdgcn_readfirstlane(cellStart[c0]);
            const int e = __builtin_amdgcn_readfirstlane(cellStart[c0 + zext]);
            const int len = ok ? (e - s) : 0;
            const int a = s - total;
            switch (u) {   // unrolled -> scalars, not an indexed array
                case 0: adj0 = a; break;
                case 1: cum1 = total; adj1 = a; break;
                case 2: cum2 = total; adj2 = a; break;
                case 3: cum3 = total; adj3 = a; break;
                case 4: cum4 = total; adj4 = a; break;
                case 5: cum5 = total; adj5 = a; break;
                case 6: cum6 = total; adj6 = a; break;
                case 7: cum7 = total; adj7 = a; break;
                case 8: cum8 = total; adj8 = a; break;
            }
            total += len;
        }

        int qn = 0;
        for (int base = 0; base < total; base += 64) {
            const int j = base + lane;
            const bool inb = (j < total);
            // r = max{u: cum[u] <= j}; pos = j + adj[r]. cum/adj are SGPRs.
            int pa = adj0;
            pa = (j >= cum1) ? adj1 : pa;
            pa = (j >= cum2) ? adj2 : pa;
            pa = (j >= cum3) ? adj3 : pa;
            pa = (j >= cum4) ? adj4 : pa;
            pa = (j >= cum5) ? adj5 : pa;
            pa = (j >= cum6) ? adj6 : pa;
            pa = (j >= cum7) ? adj7 : pa;
            pa = (j >= cum8) ? adj8 : pa;
            const int pos = inb ? (j + pa) : 0;
            float4 c = sp[pos];                    // one ds_read_b128
            float dx = c.x - qx, dy = c.y - qy, dz = c.z - qz;
            float ds = fmaf(dz, dz, fmaf(dy, dy, dx * dx));
            bool qual = inb && (ds <= RAD2);
            unsigned long long m = __ballot(qual);
            if (m) {
                if (qual) {
                    unsigned r = __builtin_amdgcn_mbcnt_lo((unsigned)m, 0u);
                    r = __builtin_amdgcn_mbcnt_hi((unsigned)(m >> 32), r);
                    int w = qn + (int)r;
                    if (w < QCAP) {
                        qds[wid][w] = ds;
                        qid[wid][w] = (unsigned short)__float_as_int(c.w);
                    }
                }
                qn += (int)__popcll(m);
            }
        }

        // Rank stored qualifiers by original index (readlane broadcasts;
        // iterations independent -> pipelined).
        const int qc = qn > QCAP ? QCAP : qn;   // qc >= 1 (self qualifies)
        const bool act = (lane < qc);
        float myds = qds[wid][act ? lane : 0];
        int myid = act ? (int)qid[wid][lane] : 0x7fffffff;
        int rank = 0;
        for (int j2 = 0; j2 < qc; ++j2) {
            int o = __shfl(myid, j2, 64);
            rank += (o < myid) ? 1 : 0;
        }
        if (act && rank < NS) buf[(wid << 2) + q][rank] = myds;
        if (lane == 0) cnts[(wid << 2) + q] = qc < NS ? qc : NS;
    }
    __syncthreads();

    // ---- Epilogue: lane i of wave 0 handles block point i.
    if (tid < 64) {
        int cnt = cnts[tid];
        float s[NS];
        float first = buf[tid][0];   // ds of smallest-index qualifier
        #pragma unroll
        for (int j = 0; j < NS; ++j) {
            float v = buf[tid][j];
            s[j] = (j < cnt) ? v : first;
        }
        #pragma unroll
        for (int i = 0; i < 5; ++i) {   // smallest 5 ascending into s[0..4]
            #pragma unroll
            for (int j = i + 1; j < NS; ++j) {
                float lo = fminf(s[i], s[j]);
                float hi = fmaxf(s[i], s[j]);
                s[i] = lo; s[j] = hi;
            }
        }
        float acc = 0.0f;
        #pragma unroll
        for (int i = 1; i < 5; ++i) {
            float c = (s[i] < EPSV) ? EPSV : s[i];
            acc += 0.1f - sqrtf(c) * expf(-c / H2);
        }
        #pragma unroll
        for (int o = 32; o >= 1; o >>= 1)
            acc += __shfl_down(acc, o, 64);
        if (tid == 0) part[blockIdx.x] = acc;   // plain store, no atomic
    }
}

__global__ __launch_bounds__(512) void reduce_kernel(
    const float* __restrict__ part, float* __restrict__ out) {
    __shared__ float w[8];
    const int tid = threadIdx.x;
    float s = part[tid];               // 512 partials, 512 threads
    #pragma unroll
    for (int o = 32; o >= 1; o >>= 1)
        s += __shfl_down(s, o, 64);
    if ((tid & 63) == 0) w[tid >> 6] = s;
    __syncthreads();
    if (tid == 0) {
        float t = 0.0f;
        #pragma unroll
        for (int i = 0; i < 8; ++i) t += w[i];
        out[0] = t * SCALE;
    }
}

extern "C" void kernel_launch(void* const* d_in, const int* in_sizes, int n_in,
                              void* d_out, int out_size, void* d_ws, size_t ws_size,
                              hipStream_t stream) {
    const float* pred = (const float*)d_in[0];
    float* out = (float*)d_out;
    float* part = (float*)d_ws;        // 512 floats of the workspace
    density_loss_kernel<<<dim3(NB * 64), dim3(1024), 0, stream>>>(pred, part);
    reduce_kernel<<<dim3(1), dim3(512), 0, stream>>>(part, out);
}